// Round 5
// baseline (169.617 us; speedup 1.0000x reference)
//
#include <hip/hip_runtime.h>
#include <math.h>

#define SEQ 2048
#define DM  1024
#define DI  64

typedef __attribute__((ext_vector_type(8))) short short8;
typedef __attribute__((ext_vector_type(4))) float f32x4;
typedef __attribute__((ext_vector_type(4))) unsigned short ush4;

#define MFMA16(a,b,c) __builtin_amdgcn_mfma_f32_16x16x32_bf16(a,b,c,0,0,0)

// round-to-nearest-even fp32 -> bf16
__device__ __forceinline__ unsigned short f2bf(float f) {
    unsigned int u = __builtin_bit_cast(unsigned int, f);
    u += 0x7fffu + ((u >> 16) & 1u);
    return (unsigned short)(u >> 16);
}

// ---------------------------------------------------------------------------
// Kernel 0: weight prep.  blocks 0..47: Wcat^T bf16 [192][1024] (rows 0-63 =
// Wq^T * 0.125 (exact pow2 fold of 1/sqrt(64)), 64-127 = Wk^T, 128-191 = Wv^T).
// block 48: W0^T bf16 [64][64] + bcat[192] fp32 (bq*0.125 | bk | bv).
// ---------------------------------------------------------------------------
__global__ __launch_bounds__(256)
void convert_kernel(const float* __restrict__ Wq, const float* __restrict__ Wk,
                    const float* __restrict__ Wv, const float* __restrict__ W0,
                    const float* __restrict__ bq, const float* __restrict__ bk,
                    const float* __restrict__ bv,
                    unsigned short* __restrict__ Wt, unsigned short* __restrict__ W0t,
                    float* __restrict__ bcat)
{
    __shared__ float tile[64][65];
    const int t = threadIdx.x;
    const int blk = blockIdx.x;
    const float* src; unsigned short* dst; int k0; float scale; int rstride;
    if (blk < 48) {
        const int mm = blk >> 4, kt = blk & 15;
        src = (mm == 0) ? Wq : (mm == 1) ? Wk : Wv;
        dst = Wt + (size_t)mm * 64 * 1024;
        k0 = kt * 64; scale = (mm == 0) ? 0.125f : 1.0f; rstride = 1024;
    } else {
        src = W0; dst = W0t; k0 = 0; scale = 1.0f; rstride = 64;
        if (t < 192)
            bcat[t] = (t < 64) ? bq[t] * 0.125f : (t < 128) ? bk[t - 64] : bv[t - 128];
    }
#pragma unroll
    for (int i = 0; i < 4; ++i) {
        const int e = i * 1024 + t * 4;
        const int kk = e >> 6, o = e & 63;
        const float4 v = *(const float4*)(src + (size_t)(k0 + kk) * 64 + o);
        tile[kk][o] = v.x; tile[kk][o + 1] = v.y; tile[kk][o + 2] = v.z; tile[kk][o + 3] = v.w;
    }
    __syncthreads();
#pragma unroll
    for (int h = 0; h < 2; ++h) {
        const int o = (t >> 3) + 32 * h;
        const int kp = (t & 7) * 8;
        union { short8 v; unsigned short u[8]; } pk;
#pragma unroll
        for (int j = 0; j < 8; ++j) pk.u[j] = f2bf(tile[kp + j][o] * scale);
        *(short8*)(dst + (size_t)o * rstride + k0 + kp) = pk.v;
    }
}

// ---------------------------------------------------------------------------
// Kernel 1: QKV projection.  512 blocks (32-token tiles) x 4 waves splitting
// N (wave w: outs [48w,48w+48)).  The ENTIRE 32x1024 X tile is staged ONCE
// into a 64 KB bf16 LDS buffer, layout Xs[k8][token ^ (k8&7)][8]:
//   - staging writes: 8 lanes/row with g=k8&7 -> XOR makes banks distinct
//   - A-frag reads: 16 lanes/quad share k8, token=16tt+n -> 2-way (free)
// Then a BARRIER-FREE 16-step K loop (6 W-loads + 4 LDS b128 + 12 MFMA per
// step, unroll 4): loads pipeline across steps with no vmcnt drains.
// Epilogue via LDS transpose (reuses Xs).  3 barriers total.
// ---------------------------------------------------------------------------
__global__ __launch_bounds__(256, 2)
void proj_kernel(const float* __restrict__ X, const unsigned short* __restrict__ Wt,
                 const float* __restrict__ bcat,
                 unsigned short* __restrict__ Qg, unsigned short* __restrict__ Kg,
                 unsigned short* __restrict__ Vtg)
{
    __shared__ alignas(16) unsigned short Xs[128 * 32 * 8];    // exactly 64 KB
    const int t = threadIdx.x;
    const int lane = t & 63, w = t >> 6;
    const int quad = lane >> 4, n = lane & 15;
    const int r0 = blockIdx.x * 32;

    // ---- stage X tile (fp32 -> bf16), swizzled ----
    {
        const int row = t >> 3, g = t & 7;
        const float* xp = X + (size_t)(r0 + row) * DM + g * 8;
        const int wslot = (row ^ g) * 8;
#pragma unroll
        for (int i = 0; i < 16; ++i) {
            const int k8 = g + 8 * i;
            const float4 a4 = *(const float4*)(xp + i * 64);
            const float4 b4 = *(const float4*)(xp + i * 64 + 4);
            union { short8 v; unsigned short u[8]; } px;
            px.u[0]=f2bf(a4.x); px.u[1]=f2bf(a4.y); px.u[2]=f2bf(a4.z); px.u[3]=f2bf(a4.w);
            px.u[4]=f2bf(b4.x); px.u[5]=f2bf(b4.y); px.u[6]=f2bf(b4.z); px.u[7]=f2bf(b4.w);
            *(short8*)(Xs + k8 * 256 + wslot) = px.v;
        }
    }
    __syncthreads();

    const f32x4 ZERO = {0.f, 0.f, 0.f, 0.f};
    f32x4 acc[2][3];
#pragma unroll
    for (int a = 0; a < 2; ++a)
#pragma unroll
        for (int j = 0; j < 3; ++j) acc[a][j] = ZERO;

    const unsigned short* wp0 = Wt + (size_t)((3*w + 0)*16 + n) * DM + quad * 8;
    const unsigned short* wp1 = Wt + (size_t)((3*w + 1)*16 + n) * DM + quad * 8;
    const unsigned short* wp2 = Wt + (size_t)((3*w + 2)*16 + n) * DM + quad * 8;

    // ---- barrier-free K loop ----
#pragma unroll 4
    for (int ks = 0; ks < 16; ++ks) {
        const int k0 = ks * 64;
        short8 bfr[3][2];
#pragma unroll
        for (int s = 0; s < 2; ++s) {
            bfr[0][s] = *(const short8*)(wp0 + k0 + s * 32);
            bfr[1][s] = *(const short8*)(wp1 + k0 + s * 32);
            bfr[2][s] = *(const short8*)(wp2 + k0 + s * 32);
        }
        short8 af[2][2];
#pragma unroll
        for (int tt = 0; tt < 2; ++tt)
#pragma unroll
            for (int s = 0; s < 2; ++s) {
                const int k8 = ks * 8 + s * 4 + quad;          // k8 & 7 = s*4+quad
                const int tok = (16 * tt + n) ^ (s * 4 + quad);
                af[tt][s] = *(const short8*)(Xs + k8 * 256 + tok * 8);
            }
#pragma unroll
        for (int tt = 0; tt < 2; ++tt)
#pragma unroll
            for (int j = 0; j < 3; ++j) {
                acc[tt][j] = MFMA16(af[tt][0], bfr[j][0], acc[tt][j]);
                acc[tt][j] = MFMA16(af[tt][1], bfr[j][1], acc[tt][j]);
            }
    }

    __syncthreads();                                           // everyone done with Xs
    unsigned short (*Facc)[200] = (unsigned short (*)[200])Xs; // 12.8 KB reuse
    float bias[3];
#pragma unroll
    for (int j = 0; j < 3; ++j) bias[j] = bcat[(3*w + j)*16 + n];
    // D layout: col = lane&15 (out-in-tile), row = quad*4+reg (token-in-16)
#pragma unroll
    for (int tt = 0; tt < 2; ++tt)
#pragma unroll
        for (int j = 0; j < 3; ++j)
#pragma unroll
            for (int r = 0; r < 4; ++r)
                Facc[tt*16 + quad*4 + r][(3*w + j)*16 + n] = f2bf(acc[tt][j][r] + bias[j]);
    __syncthreads();
    // Q/K row-major stores: thread -> token t>>3, 8 cols
    {
        const int tok = t >> 3, c0 = (t & 7) * 8;
        *(short8*)(Qg + (size_t)(r0 + tok) * DI + c0) = *(const short8*)&Facc[tok][c0];
        *(short8*)(Kg + (size_t)(r0 + tok) * DI + c0) = *(const short8*)&Facc[tok][64 + c0];
    }
    // V^T store [b][dv][t]
    {
        const int dv = t & 63, tg = t >> 6;
        union { short8 v; unsigned short u[8]; } ov;
#pragma unroll
        for (int i = 0; i < 8; ++i) ov.u[i] = Facc[tg*8 + i][128 + dv];
        const int bidx = r0 >> 11, tloc = r0 & 2047;
        *(short8*)(Vtg + (size_t)bidx * DI * SEQ + (size_t)dv * SEQ + tloc + tg*8) = ov.v;
    }
}

// ---------------------------------------------------------------------------
// Kernel 2: split-K flash attention + fused W0.  1024 blocks = 8 batches x
// 128 q-tiles (16 rows), block 256 = 4 waves, launch_bounds(256,3) -> 3
// blocks/CU resident (12 waves/CU for latency hiding).  Wave w owns chunks
// kt = w, w+4, ... with its OWN softmax state and private P buffer -> zero
// barriers in the chunk loop.  V-loads hoisted to chunk start to overlap the
// S-MFMA/softmax chain.  qt heavy-first; b = idx&7 (XCD K/V L2 affinity).
// ---------------------------------------------------------------------------
__global__ __launch_bounds__(256, 3)
void attn_kernel(const unsigned short* __restrict__ Qg, const unsigned short* __restrict__ Kg,
                 const unsigned short* __restrict__ Vtg, const unsigned short* __restrict__ W0t,
                 const float* __restrict__ b0, float* __restrict__ Out)
{
    __shared__ alignas(16) unsigned short P[4][16][72];   // per-wave P (A-frag layout)
    __shared__ alignas(16) float Ctx[4][16][72];          // per-wave partial ctx
    __shared__ float Mw[4][16], Lw[4][16];
    __shared__ alignas(16) unsigned short Cb[16][72];     // merged ctx, bf16 A-frag layout
    const int t = threadIdx.x;
    const int lane = t & 63, w = t >> 6;
    const int quad = lane >> 4, n = lane & 15;
    const int idx = blockIdx.x;
    const int qt = 127 - (idx >> 3);
    const int b = idx & 7;
    const int q0 = qt * 16;

    const unsigned short* Qb = Qg + ((size_t)b * SEQ + q0) * DI;
    const unsigned short* Kb = Kg + (size_t)b * SEQ * DI;
    const unsigned short* Vb = Vtg + (size_t)b * DI * SEQ;

    const short8 qf0 = *(const short8*)(Qb + n * DI + quad * 8);
    const short8 qf1 = *(const short8*)(Qb + n * DI + 32 + quad * 8);

    const f32x4 ZERO = {0.f, 0.f, 0.f, 0.f};
    float m = -INFINITY, l = 0.f;
    f32x4 ctx[4];
#pragma unroll
    for (int i = 0; i < 4; ++i) ctx[i] = ZERO;

    const int C = (qt >> 2) + 1;                          // causal 64-key chunks
    for (int kt = w; kt < C; kt += 4) {
        const int k0 = kt * 64;
        // issue K AND V loads up front (independent; overlap softmax chain)
        short8 kf[4][2], vf[4][2];
#pragma unroll
        for (int tt = 0; tt < 4; ++tt) {
            const unsigned short* kr = Kb + (size_t)(k0 + 16 * tt + n) * DI + quad * 8;
            kf[tt][0] = *(const short8*)kr;
            kf[tt][1] = *(const short8*)(kr + 32);
            const unsigned short* vr = Vb + (size_t)(16 * tt + n) * SEQ + k0 + quad * 8;
            vf[tt][0] = *(const short8*)vr;
            vf[tt][1] = *(const short8*)(vr + 32);
        }
        f32x4 sv[4];
#pragma unroll
        for (int tt = 0; tt < 4; ++tt) {                  // S^T tile: rows = keys
            f32x4 a = MFMA16(kf[tt][0], qf0, ZERO);
            sv[tt] = MFMA16(kf[tt][1], qf1, a);           // S^T[key=k0+16t+quad*4+r][q=q0+n]
        }
        if (kt == C - 1) {                                // diagonal chunk: causal mask
#pragma unroll
            for (int tt = 0; tt < 4; ++tt)
#pragma unroll
                for (int r = 0; r < 4; ++r)
                    if (k0 + 16 * tt + quad * 4 + r > q0 + n) sv[tt][r] = -INFINITY;
        }
        float rmax = sv[0][0];
#pragma unroll
        for (int tt = 0; tt < 4; ++tt)
#pragma unroll
            for (int r = 0; r < 4; ++r) rmax = fmaxf(rmax, sv[tt][r]);
        rmax = fmaxf(rmax, __shfl_xor(rmax, 16));
        rmax = fmaxf(rmax, __shfl_xor(rmax, 32));
        const float mnew = fmaxf(m, rmax);
        const float alpha = __expf(m - mnew);             // first chunk: exp(-inf)=0
        float rsum = 0.f;
#pragma unroll
        for (int tt = 0; tt < 4; ++tt) {
            union { ush4 v; unsigned short u[4]; } pw;
#pragma unroll
            for (int r = 0; r < 4; ++r) {
                const float p = __expf(sv[tt][r] - mnew);
                rsum += p;
                pw.u[r] = f2bf(p);
            }
            *(ush4*)&P[w][n][16 * tt + quad * 4] = pw.v;  // P[q][key] (wave-private)
        }
        rsum += __shfl_xor(rsum, 16);
        rsum += __shfl_xor(rsum, 32);
        l = l * alpha + rsum;
        m = mnew;
        float aL[4];
#pragma unroll
        for (int r = 0; r < 4; ++r) aL[r] = __shfl(alpha, quad * 4 + r);
#pragma unroll
        for (int nt = 0; nt < 4; ++nt)
#pragma unroll
            for (int r = 0; r < 4; ++r) ctx[nt][r] *= aL[r];
#pragma unroll
        for (int s = 0; s < 2; ++s) {                     // ctx += P V
            const short8 pf = *(const short8*)&P[w][n][s * 32 + quad * 8];
#pragma unroll
            for (int nt = 0; nt < 4; ++nt)
                ctx[nt] = MFMA16(pf, vf[nt][s], ctx[nt]);
        }
    }
    // publish per-wave partials.  ctx[nt][r]: q=quad*4+r, dv=16nt+n.
#pragma unroll
    for (int nt = 0; nt < 4; ++nt)
#pragma unroll
        for (int r = 0; r < 4; ++r)
            Ctx[w][quad * 4 + r][nt * 16 + n] = ctx[nt][r];
    if (quad == 0) { Mw[w][n] = m; Lw[w][n] = l; }        // stats replicated over quads
    __syncthreads();

    // LSE merge: thread t -> q = t>>4, dv = (t&15)*4 .. +3
    {
        const int q = t >> 4, c0 = (t & 15) * 4;
        const float m0 = Mw[0][q], m1 = Mw[1][q], m2 = Mw[2][q], m3 = Mw[3][q];
        const float mstar = fmaxf(fmaxf(m0, m1), fmaxf(m2, m3));
        const float s0 = __expf(m0 - mstar), s1 = __expf(m1 - mstar);
        const float s2 = __expf(m2 - mstar), s3 = __expf(m3 - mstar);
        const float lstar = s0 * Lw[0][q] + s1 * Lw[1][q] + s2 * Lw[2][q] + s3 * Lw[3][q];
        const float4 c0v = *(const float4*)&Ctx[0][q][c0];
        const float4 c1v = *(const float4*)&Ctx[1][q][c0];
        const float4 c2v = *(const float4*)&Ctx[2][q][c0];
        const float4 c3v = *(const float4*)&Ctx[3][q][c0];
        const float inv = 1.0f / lstar;
        union { ush4 v; unsigned short u[4]; } cb;
        cb.u[0] = f2bf((s0 * c0v.x + s1 * c1v.x + s2 * c2v.x + s3 * c3v.x) * inv);
        cb.u[1] = f2bf((s0 * c0v.y + s1 * c1v.y + s2 * c2v.y + s3 * c3v.y) * inv);
        cb.u[2] = f2bf((s0 * c0v.z + s1 * c1v.z + s2 * c2v.z + s3 * c3v.z) * inv);
        cb.u[3] = f2bf((s0 * c0v.w + s1 * c1v.w + s2 * c2v.w + s3 * c3v.w) * inv);
        *(ush4*)&Cb[q][c0] = cb.v;
    }
    __syncthreads();

    // W0 epilogue: wave w computes output columns 16w..16w+15
    f32x4 oacc = ZERO;
#pragma unroll
    for (int s = 0; s < 2; ++s) {
        const short8 cf = *(const short8*)&Cb[n][s * 32 + quad * 8];
        const short8 wf = *(const short8*)(W0t + (size_t)(16 * w + n) * DI + s * 32 + quad * 8);
        oacc = MFMA16(cf, wf, oacc);
    }
    const float bb = b0[16 * w + n];
#pragma unroll
    for (int r = 0; r < 4; ++r)
        Out[((size_t)b * SEQ + q0 + quad * 4 + r) * DI + 16 * w + n] = oacc[r] + bb;
}

// ---------------------------------------------------------------------------
extern "C" void kernel_launch(void* const* d_in, const int* in_sizes, int n_in,
                              void* d_out, int out_size, void* d_ws, size_t ws_size,
                              hipStream_t stream) {
    const float* X  = (const float*)d_in[0];
    const float* Wk = (const float*)d_in[1];
    const float* bk = (const float*)d_in[2];
    const float* Wq = (const float*)d_in[3];
    const float* bq = (const float*)d_in[4];
    const float* Wv = (const float*)d_in[5];
    const float* bv = (const float*)d_in[6];
    const float* W0 = (const float*)d_in[7];
    const float* b0 = (const float*)d_in[8];
    float* Out = (float*)d_out;

    unsigned char* ws = (unsigned char*)d_ws;
    unsigned short* Wt   = (unsigned short*)ws;                       // 384 KiB
    unsigned short* W0t  = (unsigned short*)(ws + 393216);            // 8 KiB
    float*          bcat = (float*)(ws + 401408);                     // 768 B
    unsigned short* Qw   = (unsigned short*)(ws + 409600);            // 2 MiB
    unsigned short* Kw   = (unsigned short*)(ws + 409600 + 2097152);  // 2 MiB
    unsigned short* Vt   = (unsigned short*)(ws + 409600 + 4194304);  // 2 MiB

    convert_kernel<<<49, 256, 0, stream>>>(Wq, Wk, Wv, W0, bq, bk, bv, Wt, W0t, bcat);
    proj_kernel<<<512, 256, 0, stream>>>(X, Wt, bcat, Qw, Kw, Vt);
    attn_kernel<<<1024, 256, 0, stream>>>(Qw, Kw, Vt, W0t, b0, Out);
}